// Round 1
// baseline (4049.671 us; speedup 1.0000x reference)
//
#include <hip/hip_runtime.h>
#include <math.h>

// ---------------- model constants ----------------
constexpr int LAYERS = 2;
constexpr int H      = 1024;
constexpr int NH     = 16;
constexpr int HD     = 64;
constexpr int NKV    = 4;
constexpr int KVD    = 256;   // NKV*HD
constexpr int IDIM   = 2816;
constexpr int VOCAB  = 32000;
constexpr int RR     = 64;    // lora rank
constexpr int SEQ    = 512;
constexpr float LORA_SCALE = 0.25f;   // 16/64
constexpr float RMS_EPS    = 1e-6f;

__device__ __forceinline__ float dot4(float4 a, float4 b) {
    return a.x*b.x + a.y*b.y + a.z*b.z + a.w*b.w;
}

// ---------------- embedding gather ----------------
__global__ __launch_bounds__(256) void k_embed(const int* __restrict__ ids,
                                               const float* __restrict__ embed,
                                               float* __restrict__ h) {
    int s = blockIdx.x;
    int t = threadIdx.x;                       // 256 threads, H/4 = 256 float4
    const float4* src = (const float4*)(embed + (size_t)ids[s] * H);
    float4* dst = (float4*)(h + (size_t)s * H);
    dst[t] = src[t];
}

// ---------------- rmsnorm ----------------
__global__ __launch_bounds__(256) void k_rmsnorm(const float* __restrict__ h,
                                                 const float* __restrict__ w,
                                                 float* __restrict__ x) {
    __shared__ float red[4];
    int s = blockIdx.x, t = threadIdx.x;
    float4 a = ((const float4*)(h + (size_t)s * H))[t];
    float ss = a.x*a.x + a.y*a.y + a.z*a.z + a.w*a.w;
    #pragma unroll
    for (int o = 32; o > 0; o >>= 1) ss += __shfl_xor(ss, o, 64);
    if ((t & 63) == 0) red[t >> 6] = ss;
    __syncthreads();
    float tot = red[0] + red[1] + red[2] + red[3];
    float scale = rsqrtf(tot * (1.0f / H) + RMS_EPS);
    float4 wv = ((const float4*)w)[t];
    float4 o4 = make_float4(a.x*scale*wv.x, a.y*scale*wv.y, a.z*scale*wv.z, a.w*scale*wv.w);
    ((float4*)(x + (size_t)s * H))[t] = o4;
}

// ---------------- generic fused dequant/LoRA tiled linear ----------------
// y[M=512, N] (+)= x[512,K] @ W^T   with W either dequant(idx,am,cb) or plain wf,
// plus (z==0 blocks only) LORA_SCALE * (lt[512,R] @ Bm^T).
// ATOMIC: split-K over blockIdx.z with atomicAdd epilogue (y must be pre-inited).
template<int BM, int BN, bool QUANT, bool LORA, bool ATOMIC>
__global__ __launch_bounds__(256) void k_linq(
    const float* __restrict__ x, const int* __restrict__ widx,
    const float* __restrict__ wf, const float* __restrict__ am,
    const float* __restrict__ cb, const float* __restrict__ lt,
    const float* __restrict__ Bm, float* __restrict__ y,
    int N, int K, int kspan)
{
    constexpr int RTM = BM / 16;  // rows per thread
    constexpr int RTN = BN / 16;  // cols per thread
    __shared__ float xs[BM][68];
    __shared__ float ws[BN][68];
    __shared__ float cbs[16];
    const int t = threadIdx.x;
    const int sbase = blockIdx.x * BM;
    const int nbase = blockIdx.y * BN;
    if constexpr (QUANT) { if (t < 16) cbs[t] = cb[t]; }
    __syncthreads();
    int kstart = 0, kend = K;
    if constexpr (ATOMIC) { kstart = blockIdx.z * kspan; kend = min(K, kstart + kspan); }
    const int KB = K >> 6;
    float acc[RTM][RTN];
    #pragma unroll
    for (int i = 0; i < RTM; ++i)
        #pragma unroll
        for (int j = 0; j < RTN; ++j) acc[i][j] = 0.f;
    const int ty = (t >> 4) * RTM;
    const int tx = (t & 15) * RTN;

    for (int k0 = kstart; k0 < kend; k0 += 64) {
        #pragma unroll
        for (int i = 0; i < BM / 16; ++i) {
            int id = t + i * 256; int row = id >> 4; int c4 = (id & 15) << 2;
            *(float4*)&xs[row][c4] = *(const float4*)&x[(size_t)(sbase + row) * K + k0 + c4];
        }
        #pragma unroll
        for (int i = 0; i < BN / 16; ++i) {
            int id = t + i * 256; int row = id >> 4; int c4 = (id & 15) << 2;
            if constexpr (QUANT) {
                int4 iv = *(const int4*)&widx[(size_t)(nbase + row) * K + k0 + c4];
                float amv = am[(size_t)(nbase + row) * KB + (k0 >> 6)];
                *(float4*)&ws[row][c4] = make_float4(cbs[iv.x]*amv, cbs[iv.y]*amv,
                                                     cbs[iv.z]*amv, cbs[iv.w]*amv);
            } else {
                *(float4*)&ws[row][c4] = *(const float4*)&wf[(size_t)(nbase + row) * K + k0 + c4];
            }
        }
        __syncthreads();
        #pragma unroll
        for (int kk = 0; kk < 64; kk += 4) {
            float4 av[RTM], bv[RTN];
            #pragma unroll
            for (int i = 0; i < RTM; ++i) av[i] = *(const float4*)&xs[ty + i][kk];
            #pragma unroll
            for (int j = 0; j < RTN; ++j) bv[j] = *(const float4*)&ws[tx + j][kk];
            #pragma unroll
            for (int i = 0; i < RTM; ++i)
                #pragma unroll
                for (int j = 0; j < RTN; ++j) acc[i][j] += dot4(av[i], bv[j]);
        }
        __syncthreads();
    }

    const bool isz0 = (!ATOMIC) || (blockIdx.z == 0);
    if constexpr (LORA) {
        if (isz0) {   // blockIdx.z uniform per block -> sync-safe
            #pragma unroll
            for (int i = 0; i < BM / 16; ++i) {
                int id = t + i * 256; int row = id >> 4; int c4 = (id & 15) << 2;
                float4 tv = *(const float4*)&lt[(size_t)(sbase + row) * RR + c4];
                tv.x *= LORA_SCALE; tv.y *= LORA_SCALE; tv.z *= LORA_SCALE; tv.w *= LORA_SCALE;
                *(float4*)&xs[row][c4] = tv;
            }
            #pragma unroll
            for (int i = 0; i < BN / 16; ++i) {
                int id = t + i * 256; int row = id >> 4; int c4 = (id & 15) << 2;
                *(float4*)&ws[row][c4] = *(const float4*)&Bm[(size_t)(nbase + row) * RR + c4];
            }
            __syncthreads();
            #pragma unroll
            for (int kk = 0; kk < 64; kk += 4) {
                float4 av[RTM], bv[RTN];
                #pragma unroll
                for (int i = 0; i < RTM; ++i) av[i] = *(const float4*)&xs[ty + i][kk];
                #pragma unroll
                for (int j = 0; j < RTN; ++j) bv[j] = *(const float4*)&ws[tx + j][kk];
                #pragma unroll
                for (int i = 0; i < RTM; ++i)
                    #pragma unroll
                    for (int j = 0; j < RTN; ++j) acc[i][j] += dot4(av[i], bv[j]);
            }
        }
    }

    #pragma unroll
    for (int i = 0; i < RTM; ++i) {
        #pragma unroll
        for (int j = 0; j < RTN; j += 4) {
            size_t off = (size_t)(sbase + ty + i) * N + (nbase + tx + j);
            if constexpr (ATOMIC) {
                atomicAdd(&y[off + 0], acc[i][j + 0]);
                atomicAdd(&y[off + 1], acc[i][j + 1]);
                atomicAdd(&y[off + 2], acc[i][j + 2]);
                atomicAdd(&y[off + 3], acc[i][j + 3]);
            } else {
                *(float4*)&y[off] = make_float4(acc[i][j], acc[i][j+1], acc[i][j+2], acc[i][j+3]);
            }
        }
    }
}

// ---------------- RoPE (rotate-half, llama) on q and k in place ----------------
__global__ __launch_bounds__(64) void k_rope(float* __restrict__ q, float* __restrict__ k) {
    int s  = blockIdx.x;
    int hs = blockIdx.y;          // 0..15 -> q heads, 16..19 -> kv heads
    int d  = threadIdx.x;         // 0..63
    float* p = (hs < NH) ? q + ((size_t)s * NH + hs) * HD
                         : k + ((size_t)s * NKV + (hs - NH)) * HD;
    int j = d & 31;
    float inv = powf(10000.0f, -(float)(2 * j) / 64.0f);
    float ang = (float)s * inv;
    float c = cosf(ang), sn = sinf(ang);
    float xv = p[d];
    float other = (d < 32) ? -p[d + 32] : p[d - 32];   // single-wave block: lockstep safe
    p[d] = xv * c + other * sn;
}

// ---------------- attention scores + causal softmax ----------------
// grid: (SEQ/16, NH). attn[h][q][kq] written fully (masked entries = 0).
__global__ __launch_bounds__(256) void k_scores(const float* __restrict__ q,
                                                const float* __restrict__ k,
                                                float* __restrict__ attn) {
    int qt = blockIdx.x;          // q rows qt*16 .. +15
    int h  = blockIdx.y;
    int kvh = h >> 2;
    __shared__ float qs[16][68];
    __shared__ float ks[64][68];
    __shared__ float sc[16][528];
    int t = threadIdx.x;
    { int row = t >> 4; int c4 = (t & 15) << 2;
      *(float4*)&qs[row][c4] = *(const float4*)&q[(size_t)(qt*16 + row) * H + h * HD + c4]; }
    for (int c = 0; c < 8; ++c) {                 // kq chunks of 64
        #pragma unroll
        for (int i = 0; i < 4; ++i) {
            int id = t + i * 256; int row = id >> 4; int c4 = (id & 15) << 2;
            *(float4*)&ks[row][c4] = *(const float4*)&k[(size_t)(c*64 + row) * KVD + kvh * HD + c4];
        }
        __syncthreads();
        int r  = t >> 4;          // q row 0..15
        int cc = (t & 15) << 2;   // 4 kq cols
        float4 acc = make_float4(0.f, 0.f, 0.f, 0.f);
        #pragma unroll
        for (int kk = 0; kk < 64; kk += 4) {
            float4 a = *(const float4*)&qs[r][kk];
            acc.x += dot4(a, *(const float4*)&ks[cc + 0][kk]);
            acc.y += dot4(a, *(const float4*)&ks[cc + 1][kk]);
            acc.z += dot4(a, *(const float4*)&ks[cc + 2][kk]);
            acc.w += dot4(a, *(const float4*)&ks[cc + 3][kk]);
        }
        acc.x *= 0.125f; acc.y *= 0.125f; acc.z *= 0.125f; acc.w *= 0.125f;
        *(float4*)&sc[r][c * 64 + cc] = acc;
        __syncthreads();
    }
    // masked softmax, 16 lanes per row
    int r = t >> 4, lane = t & 15;
    int qpos = qt * 16 + r;
    float mx = -1e30f;
    for (int c = lane; c < SEQ; c += 16) if (c <= qpos) mx = fmaxf(mx, sc[r][c]);
    #pragma unroll
    for (int o = 8; o > 0; o >>= 1) mx = fmaxf(mx, __shfl_xor(mx, o, 16));
    float sum = 0.f;
    for (int c = lane; c < SEQ; c += 16) {
        float e = (c <= qpos) ? __expf(sc[r][c] - mx) : 0.f;
        sc[r][c] = e; sum += e;
    }
    #pragma unroll
    for (int o = 8; o > 0; o >>= 1) sum += __shfl_xor(sum, o, 16);
    float inv = 1.0f / sum;
    for (int c = lane; c < SEQ; c += 16)
        attn[((size_t)h * SEQ + qpos) * SEQ + c] = sc[r][c] * inv;
}

// ---------------- ctx = attn @ v (per head), causal chunk skipping ----------------
__global__ __launch_bounds__(256) void k_ctx(const float* __restrict__ attn,
                                             const float* __restrict__ v,
                                             float* __restrict__ ctx) {
    int qt = blockIdx.x, h = blockIdx.y, kvh = h >> 2;
    __shared__ float as_[64][68];
    __shared__ float vs[64][68];
    int t = threadIdx.x;
    float acc[4][4] = {};
    for (int c = 0; c <= qt; ++c) {
        #pragma unroll
        for (int i = 0; i < 4; ++i) {
            int id = t + i * 256; int row = id >> 4; int c4 = (id & 15) << 2;
            *(float4*)&as_[row][c4] = *(const float4*)&attn[((size_t)h*SEQ + qt*64 + row) * SEQ + c*64 + c4];
            *(float4*)&vs[row][c4]  = *(const float4*)&v[(size_t)(c*64 + row) * KVD + kvh * HD + c4];
        }
        __syncthreads();
        int ty = (t >> 4) * 4, tx = (t & 15) * 4;
        #pragma unroll
        for (int kk = 0; kk < 64; ++kk) {
            float4 b = *(const float4*)&vs[kk][tx];
            #pragma unroll
            for (int i = 0; i < 4; ++i) {
                float a = as_[ty + i][kk];
                acc[i][0] += a * b.x; acc[i][1] += a * b.y;
                acc[i][2] += a * b.z; acc[i][3] += a * b.w;
            }
        }
        __syncthreads();
    }
    int ty = (t >> 4) * 4, tx = (t & 15) * 4;
    #pragma unroll
    for (int i = 0; i < 4; ++i)
        *(float4*)&ctx[(size_t)(qt*64 + ty + i) * H + h * HD + tx] =
            make_float4(acc[i][0], acc[i][1], acc[i][2], acc[i][3]);
}

// ---------------- silu(gate)*up ----------------
__global__ __launch_bounds__(256) void k_silu(const float* __restrict__ g,
                                              const float* __restrict__ u,
                                              float* __restrict__ o, int n4) {
    int i = blockIdx.x * 256 + threadIdx.x;
    if (i < n4) {
        float4 gv = ((const float4*)g)[i];
        float4 uv = ((const float4*)u)[i];
        float4 r;
        r.x = gv.x / (1.f + __expf(-gv.x)) * uv.x;
        r.y = gv.y / (1.f + __expf(-gv.y)) * uv.y;
        r.z = gv.z / (1.f + __expf(-gv.z)) * uv.z;
        r.w = gv.w / (1.f + __expf(-gv.w)) * uv.w;
        ((float4*)o)[i] = r;
    }
}

// ---------------- host launcher ----------------
extern "C" void kernel_launch(void* const* d_in, const int* in_sizes, int n_in,
                              void* d_out, int out_size, void* d_ws, size_t ws_size,
                              hipStream_t stream) {
    const int*   p_ids   = (const int*)  d_in[0];
    const float* p_embed = (const float*)d_in[1];
    const float* p_cb    = (const float*)d_in[2];
    const int*   p_qidx  = (const int*)  d_in[3];  const float* p_qam = (const float*)d_in[4];
    const float* p_qA    = (const float*)d_in[5];  const float* p_qB  = (const float*)d_in[6];
    const int*   p_kidx  = (const int*)  d_in[7];  const float* p_kam = (const float*)d_in[8];
    const float* p_kA    = (const float*)d_in[9];  const float* p_kB  = (const float*)d_in[10];
    const int*   p_vidx  = (const int*)  d_in[11]; const float* p_vam = (const float*)d_in[12];
    const float* p_vA    = (const float*)d_in[13]; const float* p_vB  = (const float*)d_in[14];
    const int*   p_oidx  = (const int*)  d_in[15]; const float* p_oam = (const float*)d_in[16];
    const float* p_oA    = (const float*)d_in[17]; const float* p_oB  = (const float*)d_in[18];
    const int*   p_gidx  = (const int*)  d_in[19]; const float* p_gam = (const float*)d_in[20];
    const float* p_gA    = (const float*)d_in[21]; const float* p_gB  = (const float*)d_in[22];
    const int*   p_uidx  = (const int*)  d_in[23]; const float* p_uam = (const float*)d_in[24];
    const float* p_uA    = (const float*)d_in[25]; const float* p_uB  = (const float*)d_in[26];
    const int*   p_didx  = (const int*)  d_in[27]; const float* p_dam = (const float*)d_in[28];
    const float* p_dA    = (const float*)d_in[29]; const float* p_dB  = (const float*)d_in[30];
    const float* p_ln1   = (const float*)d_in[31];
    const float* p_ln2   = (const float*)d_in[32];
    const float* p_fn    = (const float*)d_in[33];
    const int*   p_lmidx = (const int*)  d_in[34]; const float* p_lmam = (const float*)d_in[35];

    // workspace layout (floats): ~38 MB total
    float* hbuf = (float*)d_ws;                      // [SEQ][H]
    float* xbuf = hbuf + (size_t)SEQ * H;            // [SEQ][H]
    float* qb   = xbuf + (size_t)SEQ * H;            // [SEQ][H]
    float* kb   = qb   + (size_t)SEQ * H;            // [SEQ][KVD]
    float* vb   = kb   + (size_t)SEQ * KVD;          // [SEQ][KVD]
    float* ctx  = vb   + (size_t)SEQ * KVD;          // [SEQ][H]
    float* gate = ctx  + (size_t)SEQ * H;            // [SEQ][IDIM]
    float* up   = gate + (size_t)SEQ * IDIM;         // [SEQ][IDIM]
    float* attn = up   + (size_t)SEQ * IDIM;         // [NH][SEQ][SEQ]
    float* tbuf = attn + (size_t)NH * SEQ * SEQ;     // [SEQ][RR]

    k_embed<<<SEQ, 256, 0, stream>>>(p_ids, p_embed, hbuf);

    for (int l = 0; l < LAYERS; ++l) {
        const int*   qi  = p_qidx + (size_t)l * H * H;      const float* qa = p_qam + (size_t)l * (H*H/64);
        const float* qAl = p_qA + (size_t)l * RR * H;       const float* qBl = p_qB + (size_t)l * H * RR;
        const int*   ki  = p_kidx + (size_t)l * KVD * H;    const float* ka = p_kam + (size_t)l * (KVD*H/64);
        const float* kAl = p_kA + (size_t)l * RR * H;       const float* kBl = p_kB + (size_t)l * KVD * RR;
        const int*   vi  = p_vidx + (size_t)l * KVD * H;    const float* va = p_vam + (size_t)l * (KVD*H/64);
        const float* vAl = p_vA + (size_t)l * RR * H;       const float* vBl = p_vB + (size_t)l * KVD * RR;
        const int*   oi  = p_oidx + (size_t)l * H * H;      const float* oa = p_oam + (size_t)l * (H*H/64);
        const float* oAl = p_oA + (size_t)l * RR * H;       const float* oBl = p_oB + (size_t)l * H * RR;
        const int*   gi  = p_gidx + (size_t)l * IDIM * H;   const float* ga = p_gam + (size_t)l * (IDIM*H/64);
        const float* gAl = p_gA + (size_t)l * RR * H;       const float* gBl = p_gB + (size_t)l * IDIM * RR;
        const int*   ui  = p_uidx + (size_t)l * IDIM * H;   const float* ua = p_uam + (size_t)l * (IDIM*H/64);
        const float* uAl = p_uA + (size_t)l * RR * H;       const float* uBl = p_uB + (size_t)l * IDIM * RR;
        const int*   di  = p_didx + (size_t)l * H * IDIM;   const float* da = p_dam + (size_t)l * (H*IDIM/64);
        const float* dAl = p_dA + (size_t)l * RR * IDIM;    const float* dBl = p_dB + (size_t)l * H * RR;

        // ---- attention block ----
        k_rmsnorm<<<SEQ, 256, 0, stream>>>(hbuf, p_ln1 + (size_t)l * H, xbuf);
        // q
        hipMemsetAsync(tbuf, 0, (size_t)SEQ * RR * sizeof(float), stream);
        k_linq<64,64,false,false,true><<<dim3(8,1,8), 256, 0, stream>>>(
            xbuf, nullptr, qAl, nullptr, nullptr, nullptr, nullptr, tbuf, RR, H, 128);
        hipMemsetAsync(qb, 0, (size_t)SEQ * H * sizeof(float), stream);
        k_linq<64,64,true,true,true><<<dim3(8,16,2), 256, 0, stream>>>(
            xbuf, qi, nullptr, qa, p_cb, tbuf, qBl, qb, H, H, 512);
        // k
        hipMemsetAsync(tbuf, 0, (size_t)SEQ * RR * sizeof(float), stream);
        k_linq<64,64,false,false,true><<<dim3(8,1,8), 256, 0, stream>>>(
            xbuf, nullptr, kAl, nullptr, nullptr, nullptr, nullptr, tbuf, RR, H, 128);
        hipMemsetAsync(kb, 0, (size_t)SEQ * KVD * sizeof(float), stream);
        k_linq<64,64,true,true,true><<<dim3(8,4,4), 256, 0, stream>>>(
            xbuf, ki, nullptr, ka, p_cb, tbuf, kBl, kb, KVD, H, 256);
        // v
        hipMemsetAsync(tbuf, 0, (size_t)SEQ * RR * sizeof(float), stream);
        k_linq<64,64,false,false,true><<<dim3(8,1,8), 256, 0, stream>>>(
            xbuf, nullptr, vAl, nullptr, nullptr, nullptr, nullptr, tbuf, RR, H, 128);
        hipMemsetAsync(vb, 0, (size_t)SEQ * KVD * sizeof(float), stream);
        k_linq<64,64,true,true,true><<<dim3(8,4,4), 256, 0, stream>>>(
            xbuf, vi, nullptr, va, p_cb, tbuf, vBl, vb, KVD, H, 256);

        k_rope<<<dim3(SEQ, NH + NKV), 64, 0, stream>>>(qb, kb);
        k_scores<<<dim3(SEQ/16, NH), 256, 0, stream>>>(qb, kb, attn);
        k_ctx<<<dim3(SEQ/64, NH), 256, 0, stream>>>(attn, vb, ctx);

        // o-projection, accumulated in place into residual h
        hipMemsetAsync(tbuf, 0, (size_t)SEQ * RR * sizeof(float), stream);
        k_linq<64,64,false,false,true><<<dim3(8,1,8), 256, 0, stream>>>(
            ctx, nullptr, oAl, nullptr, nullptr, nullptr, nullptr, tbuf, RR, H, 128);
        k_linq<64,64,true,true,true><<<dim3(8,16,2), 256, 0, stream>>>(
            ctx, oi, nullptr, oa, p_cb, tbuf, oBl, hbuf, H, H, 512);

        // ---- MLP block ----
        k_rmsnorm<<<SEQ, 256, 0, stream>>>(hbuf, p_ln2 + (size_t)l * H, xbuf);
        // gate
        hipMemsetAsync(tbuf, 0, (size_t)SEQ * RR * sizeof(float), stream);
        k_linq<64,64,false,false,true><<<dim3(8,1,8), 256, 0, stream>>>(
            xbuf, nullptr, gAl, nullptr, nullptr, nullptr, nullptr, tbuf, RR, H, 128);
        hipMemsetAsync(gate, 0, (size_t)SEQ * IDIM * sizeof(float), stream);
        k_linq<128,64,true,true,true><<<dim3(4,44,2), 256, 0, stream>>>(
            xbuf, gi, nullptr, ga, p_cb, tbuf, gBl, gate, IDIM, H, 512);
        // up
        hipMemsetAsync(tbuf, 0, (size_t)SEQ * RR * sizeof(float), stream);
        k_linq<64,64,false,false,true><<<dim3(8,1,8), 256, 0, stream>>>(
            xbuf, nullptr, uAl, nullptr, nullptr, nullptr, nullptr, tbuf, RR, H, 128);
        hipMemsetAsync(up, 0, (size_t)SEQ * IDIM * sizeof(float), stream);
        k_linq<128,64,true,true,true><<<dim3(4,44,2), 256, 0, stream>>>(
            xbuf, ui, nullptr, ua, p_cb, tbuf, uBl, up, IDIM, H, 512);

        k_silu<<<(SEQ*IDIM/4 + 255)/256, 256, 0, stream>>>(gate, up, gate, SEQ*IDIM/4);

        // down-projection (K = IDIM), accumulated in place into residual h
        hipMemsetAsync(tbuf, 0, (size_t)SEQ * RR * sizeof(float), stream);
        k_linq<64,64,false,false,true><<<dim3(8,1,11), 256, 0, stream>>>(
            gate, nullptr, dAl, nullptr, nullptr, nullptr, nullptr, tbuf, RR, IDIM, 256);
        k_linq<128,64,true,true,true><<<dim3(4,16,2), 256, 0, stream>>>(
            gate, di, nullptr, da, p_cb, tbuf, dBl, hbuf, H, IDIM, 1408);
    }

    // final norm + quantized lm_head (no LoRA)
    k_rmsnorm<<<SEQ, 256, 0, stream>>>(hbuf, p_fn, xbuf);
    k_linq<128,64,true,false,false><<<dim3(4,500,1), 256, 0, stream>>>(
        xbuf, p_lmidx, nullptr, p_lmam, p_cb, nullptr, nullptr, (float*)d_out, VOCAB, H, H);
}

// Round 2
// 1522.069 us; speedup vs baseline: 2.6606x; 2.6606x over previous
//
#include <hip/hip_runtime.h>
#include <math.h>

// ---------------- model constants ----------------
constexpr int LAYERS = 2;
constexpr int H      = 1024;
constexpr int NH     = 16;
constexpr int HD     = 64;
constexpr int NKV    = 4;
constexpr int KVD    = 256;   // NKV*HD
constexpr int IDIM   = 2816;
constexpr int VOCAB  = 32000;
constexpr int RR     = 64;    // lora rank
constexpr int SEQ    = 512;
constexpr float LORA_SCALE = 0.25f;   // 16/64
constexpr float RMS_EPS    = 1e-6f;

typedef __attribute__((ext_vector_type(8))) __bf16 bf16x8;
typedef __attribute__((ext_vector_type(8))) unsigned short u16x8;
typedef __attribute__((ext_vector_type(4))) float f32x4;

__device__ __forceinline__ float dot4(float4 a, float4 b) {
    return a.x*b.x + a.y*b.y + a.z*b.z + a.w*b.w;
}

__device__ __forceinline__ bf16x8 pack8(float4 a, float4 b) {
    bf16x8 p;
    p[0] = (__bf16)a.x; p[1] = (__bf16)a.y; p[2] = (__bf16)a.z; p[3] = (__bf16)a.w;
    p[4] = (__bf16)b.x; p[5] = (__bf16)b.y; p[6] = (__bf16)b.z; p[7] = (__bf16)b.w;
    return p;
}

__device__ __forceinline__ bf16x8 dq8(int4 a, int4 b, float amv, const float* cbs) {
    bf16x8 p;
    p[0] = (__bf16)(cbs[a.x]*amv); p[1] = (__bf16)(cbs[a.y]*amv);
    p[2] = (__bf16)(cbs[a.z]*amv); p[3] = (__bf16)(cbs[a.w]*amv);
    p[4] = (__bf16)(cbs[b.x]*amv); p[5] = (__bf16)(cbs[b.y]*amv);
    p[6] = (__bf16)(cbs[b.z]*amv); p[7] = (__bf16)(cbs[b.w]*amv);
    return p;
}

// ---------------- embedding gather ----------------
__global__ __launch_bounds__(256) void k_embed(const int* __restrict__ ids,
                                               const float* __restrict__ embed,
                                               float* __restrict__ h) {
    int s = blockIdx.x;
    int t = threadIdx.x;
    const float4* src = (const float4*)(embed + (size_t)ids[s] * H);
    float4* dst = (float4*)(h + (size_t)s * H);
    dst[t] = src[t];
}

// ---------------- rmsnorm ----------------
__global__ __launch_bounds__(256) void k_rmsnorm(const float* __restrict__ h,
                                                 const float* __restrict__ w,
                                                 float* __restrict__ x) {
    __shared__ float red[4];
    int s = blockIdx.x, t = threadIdx.x;
    float4 a = ((const float4*)(h + (size_t)s * H))[t];
    float ss = a.x*a.x + a.y*a.y + a.z*a.z + a.w*a.w;
    #pragma unroll
    for (int o = 32; o > 0; o >>= 1) ss += __shfl_xor(ss, o, 64);
    if ((t & 63) == 0) red[t >> 6] = ss;
    __syncthreads();
    float tot = red[0] + red[1] + red[2] + red[3];
    float scale = rsqrtf(tot * (1.0f / H) + RMS_EPS);
    float4 wv = ((const float4*)w)[t];
    float4 o4 = make_float4(a.x*scale*wv.x, a.y*scale*wv.y, a.z*scale*wv.z, a.w*scale*wv.w);
    ((float4*)(x + (size_t)s * H))[t] = o4;
}

// ---------------- fused dequant + LoRA MFMA GEMM ----------------
// y[512, N] (+)= x[512,K] @ dequant(widx,am,cb)^T  (+ LORA_S * lt @ Bm^T)
// 128x128 tile, 4 waves (2x2), each wave 64x64 via 4x4 mfma_f32_16x16x32_bf16.
template<bool LORA, bool ADD>
__global__ __launch_bounds__(256) void k_gemm(
    const float* __restrict__ x, const int* __restrict__ widx,
    const float* __restrict__ am, const float* __restrict__ cb,
    const float* __restrict__ lt, const float* __restrict__ Bm,
    float* __restrict__ y, int N, int K)
{
    __shared__ __align__(16) __bf16 As[128][64];
    __shared__ __align__(16) __bf16 Bs[128][64];
    __shared__ float cbs[16];
    const int t    = threadIdx.x;
    const int lane = t & 63;
    const int wave = t >> 6;
    const int wm = (wave >> 1) * 64;
    const int wn = (wave & 1) * 64;
    const int sbase = blockIdx.x * 128;
    const int nbase = blockIdx.y * 128;
    if (t < 16) cbs[t] = cb[t];

    const int srow = t >> 3;          // 0..31
    const int scol = (t & 7) * 8;     // 0,8,..,56
    const int KB   = K >> 6;

    f32x4 acc[4][4];
    const f32x4 fz = {0.f, 0.f, 0.f, 0.f};
    #pragma unroll
    for (int i = 0; i < 4; ++i)
        #pragma unroll
        for (int j = 0; j < 4; ++j) acc[i][j] = fz;

    __syncthreads();   // cbs visible

    for (int k0 = 0; k0 < K; k0 += 64) {
        // stage A: x[128][64] fp32 -> bf16
        #pragma unroll
        for (int p = 0; p < 4; ++p) {
            int row = p * 32 + srow;
            const float* xp = &x[(size_t)(sbase + row) * K + k0 + scol];
            float4 f0 = *(const float4*)xp;
            float4 f1 = *(const float4*)(xp + 4);
            *(bf16x8*)&As[row][scol] = pack8(f0, f1);
        }
        // stage B: dequant widx[128][64] -> bf16
        #pragma unroll
        for (int p = 0; p < 4; ++p) {
            int row = p * 32 + srow;
            const int* ip = &widx[(size_t)(nbase + row) * K + k0 + scol];
            int4 i0 = *(const int4*)ip;
            int4 i1 = *(const int4*)(ip + 4);
            float amv = am[(size_t)(nbase + row) * KB + (k0 >> 6)];
            *(bf16x8*)&Bs[row][scol] = dq8(i0, i1, amv, cbs);
        }
        __syncthreads();
        #pragma unroll
        for (int s = 0; s < 2; ++s) {
            bf16x8 a[4], b[4];
            #pragma unroll
            for (int mi = 0; mi < 4; ++mi)
                a[mi] = *(bf16x8*)&As[wm + mi*16 + (lane & 15)][s*32 + (lane >> 4)*8];
            #pragma unroll
            for (int ni = 0; ni < 4; ++ni)
                b[ni] = *(bf16x8*)&Bs[wn + ni*16 + (lane & 15)][s*32 + (lane >> 4)*8];
            #pragma unroll
            for (int mi = 0; mi < 4; ++mi)
                #pragma unroll
                for (int ni = 0; ni < 4; ++ni)
                    acc[mi][ni] = __builtin_amdgcn_mfma_f32_16x16x32_bf16(
                        a[mi], b[ni], acc[mi][ni], 0, 0, 0);
        }
        __syncthreads();
    }

    if constexpr (LORA) {
        // one extra K-tile: A = LORA_SCALE * lt[128][64], B = Bm[128][64]
        #pragma unroll
        for (int p = 0; p < 4; ++p) {
            int row = p * 32 + srow;
            const float* lp = &lt[(size_t)(sbase + row) * RR + scol];
            float4 f0 = *(const float4*)lp;
            float4 f1 = *(const float4*)(lp + 4);
            f0.x *= LORA_SCALE; f0.y *= LORA_SCALE; f0.z *= LORA_SCALE; f0.w *= LORA_SCALE;
            f1.x *= LORA_SCALE; f1.y *= LORA_SCALE; f1.z *= LORA_SCALE; f1.w *= LORA_SCALE;
            *(bf16x8*)&As[row][scol] = pack8(f0, f1);
            const float* bp = &Bm[(size_t)(nbase + row) * RR + scol];
            float4 g0 = *(const float4*)bp;
            float4 g1 = *(const float4*)(bp + 4);
            *(bf16x8*)&Bs[row][scol] = pack8(g0, g1);
        }
        __syncthreads();
        #pragma unroll
        for (int s = 0; s < 2; ++s) {
            bf16x8 a[4], b[4];
            #pragma unroll
            for (int mi = 0; mi < 4; ++mi)
                a[mi] = *(bf16x8*)&As[wm + mi*16 + (lane & 15)][s*32 + (lane >> 4)*8];
            #pragma unroll
            for (int ni = 0; ni < 4; ++ni)
                b[ni] = *(bf16x8*)&Bs[wn + ni*16 + (lane & 15)][s*32 + (lane >> 4)*8];
            #pragma unroll
            for (int mi = 0; mi < 4; ++mi)
                #pragma unroll
                for (int ni = 0; ni < 4; ++ni)
                    acc[mi][ni] = __builtin_amdgcn_mfma_f32_16x16x32_bf16(
                        a[mi], b[ni], acc[mi][ni], 0, 0, 0);
        }
    }

    // epilogue: C/D layout col=lane&15, row=(lane>>4)*4+reg  [m89-verified]
    const int cr = (lane >> 4) * 4;
    const int cc = lane & 15;
    #pragma unroll
    for (int mi = 0; mi < 4; ++mi) {
        #pragma unroll
        for (int ni = 0; ni < 4; ++ni) {
            int gr = sbase + wm + mi * 16 + cr;
            int gc = nbase + wn + ni * 16 + cc;
            #pragma unroll
            for (int r = 0; r < 4; ++r) {
                size_t off = (size_t)(gr + r) * N + gc;
                if constexpr (ADD) y[off] += acc[mi][ni][r];
                else               y[off]  = acc[mi][ni][r];
            }
        }
    }
}

// ---------------- LoRA tmp: out_sel[512,64] += x[512,K] @ A_sel^T (split-K) ----------------
__global__ __launch_bounds__(256) void k_lora3(
    const float* __restrict__ x, const float* __restrict__ A0,
    const float* __restrict__ A1, const float* __restrict__ A2,
    float* __restrict__ out, int K, int kspan)
{
    __shared__ float xs[64][68];
    __shared__ float ws[64][68];
    const float* A = (blockIdx.y == 0) ? A0 : (blockIdx.y == 1) ? A1 : A2;
    float* y = out + (size_t)blockIdx.y * (SEQ * RR);
    const int t = threadIdx.x;
    const int sbase = blockIdx.x * 64;
    const int kstart = blockIdx.z * kspan;
    const int kend = min(K, kstart + kspan);
    float acc[4][4] = {};
    const int ty = (t >> 4) * 4, tx = (t & 15) * 4;
    for (int k0 = kstart; k0 < kend; k0 += 64) {
        #pragma unroll
        for (int i = 0; i < 4; ++i) {
            int id = t + i * 256; int row = id >> 4; int c4 = (id & 15) << 2;
            *(float4*)&xs[row][c4] = *(const float4*)&x[(size_t)(sbase + row) * K + k0 + c4];
            *(float4*)&ws[row][c4] = *(const float4*)&A[(size_t)row * K + k0 + c4];
        }
        __syncthreads();
        #pragma unroll
        for (int kk = 0; kk < 64; kk += 4) {
            float4 av[4], bv[4];
            #pragma unroll
            for (int i = 0; i < 4; ++i) av[i] = *(const float4*)&xs[ty + i][kk];
            #pragma unroll
            for (int j = 0; j < 4; ++j) bv[j] = *(const float4*)&ws[tx + j][kk];
            #pragma unroll
            for (int i = 0; i < 4; ++i)
                #pragma unroll
                for (int j = 0; j < 4; ++j) acc[i][j] += dot4(av[i], bv[j]);
        }
        __syncthreads();
    }
    #pragma unroll
    for (int i = 0; i < 4; ++i)
        #pragma unroll
        for (int j = 0; j < 4; ++j)
            atomicAdd(&y[(size_t)(sbase + ty + i) * RR + tx + j], acc[i][j]);
}

// ---------------- RoPE (rotate-half, llama) on q and k in place ----------------
__global__ __launch_bounds__(64) void k_rope(float* __restrict__ q, float* __restrict__ k) {
    int s  = blockIdx.x;
    int hs = blockIdx.y;
    int d  = threadIdx.x;
    float* p = (hs < NH) ? q + ((size_t)s * NH + hs) * HD
                         : k + ((size_t)s * NKV + (hs - NH)) * HD;
    int j = d & 31;
    float inv = powf(10000.0f, -(float)(2 * j) / 64.0f);
    float ang = (float)s * inv;
    float c = cosf(ang), sn = sinf(ang);
    float xv = p[d];
    float other = (d < 32) ? -p[d + 32] : p[d - 32];
    p[d] = xv * c + other * sn;
}

// ---------------- attention scores + causal softmax ----------------
__global__ __launch_bounds__(256) void k_scores(const float* __restrict__ q,
                                                const float* __restrict__ k,
                                                float* __restrict__ attn) {
    int qt = blockIdx.x;
    int h  = blockIdx.y;
    int kvh = h >> 2;
    __shared__ float qs[16][68];
    __shared__ float ks[64][68];
    __shared__ float sc[16][528];
    int t = threadIdx.x;
    { int row = t >> 4; int c4 = (t & 15) << 2;
      *(float4*)&qs[row][c4] = *(const float4*)&q[(size_t)(qt*16 + row) * H + h * HD + c4]; }
    for (int c = 0; c < 8; ++c) {
        #pragma unroll
        for (int i = 0; i < 4; ++i) {
            int id = t + i * 256; int row = id >> 4; int c4 = (id & 15) << 2;
            *(float4*)&ks[row][c4] = *(const float4*)&k[(size_t)(c*64 + row) * KVD + kvh * HD + c4];
        }
        __syncthreads();
        int r  = t >> 4;
        int cc = (t & 15) << 2;
        float4 acc = make_float4(0.f, 0.f, 0.f, 0.f);
        #pragma unroll
        for (int kk = 0; kk < 64; kk += 4) {
            float4 a = *(const float4*)&qs[r][kk];
            acc.x += dot4(a, *(const float4*)&ks[cc + 0][kk]);
            acc.y += dot4(a, *(const float4*)&ks[cc + 1][kk]);
            acc.z += dot4(a, *(const float4*)&ks[cc + 2][kk]);
            acc.w += dot4(a, *(const float4*)&ks[cc + 3][kk]);
        }
        acc.x *= 0.125f; acc.y *= 0.125f; acc.z *= 0.125f; acc.w *= 0.125f;
        *(float4*)&sc[r][c * 64 + cc] = acc;
        __syncthreads();
    }
    int r = t >> 4, lane = t & 15;
    int qpos = qt * 16 + r;
    float mx = -1e30f;
    for (int c = lane; c < SEQ; c += 16) if (c <= qpos) mx = fmaxf(mx, sc[r][c]);
    #pragma unroll
    for (int o = 8; o > 0; o >>= 1) mx = fmaxf(mx, __shfl_xor(mx, o, 16));
    float sum = 0.f;
    for (int c = lane; c < SEQ; c += 16) {
        float e = (c <= qpos) ? __expf(sc[r][c] - mx) : 0.f;
        sc[r][c] = e; sum += e;
    }
    #pragma unroll
    for (int o = 8; o > 0; o >>= 1) sum += __shfl_xor(sum, o, 16);
    float inv = 1.0f / sum;
    for (int c = lane; c < SEQ; c += 16)
        attn[((size_t)h * SEQ + qpos) * SEQ + c] = sc[r][c] * inv;
}

// ---------------- ctx = attn @ v ----------------
__global__ __launch_bounds__(256) void k_ctx(const float* __restrict__ attn,
                                             const float* __restrict__ v,
                                             float* __restrict__ ctx) {
    int qt = blockIdx.x, h = blockIdx.y, kvh = h >> 2;
    __shared__ float as_[64][68];
    __shared__ float vs[64][68];
    int t = threadIdx.x;
    float acc[4][4] = {};
    for (int c = 0; c <= qt; ++c) {
        #pragma unroll
        for (int i = 0; i < 4; ++i) {
            int id = t + i * 256; int row = id >> 4; int c4 = (id & 15) << 2;
            *(float4*)&as_[row][c4] = *(const float4*)&attn[((size_t)h*SEQ + qt*64 + row) * SEQ + c*64 + c4];
            *(float4*)&vs[row][c4]  = *(const float4*)&v[(size_t)(c*64 + row) * KVD + kvh * HD + c4];
        }
        __syncthreads();
        int ty = (t >> 4) * 4, tx = (t & 15) * 4;
        #pragma unroll
        for (int kk = 0; kk < 64; ++kk) {
            float4 b = *(const float4*)&vs[kk][tx];
            #pragma unroll
            for (int i = 0; i < 4; ++i) {
                float a = as_[ty + i][kk];
                acc[i][0] += a * b.x; acc[i][1] += a * b.y;
                acc[i][2] += a * b.z; acc[i][3] += a * b.w;
            }
        }
        __syncthreads();
    }
    int ty = (t >> 4) * 4, tx = (t & 15) * 4;
    #pragma unroll
    for (int i = 0; i < 4; ++i)
        *(float4*)&ctx[(size_t)(qt*64 + ty + i) * H + h * HD + tx] =
            make_float4(acc[i][0], acc[i][1], acc[i][2], acc[i][3]);
}

// ---------------- silu(gate)*up ----------------
__global__ __launch_bounds__(256) void k_silu(const float* __restrict__ g,
                                              const float* __restrict__ u,
                                              float* __restrict__ o, int n4) {
    int i = blockIdx.x * 256 + threadIdx.x;
    if (i < n4) {
        float4 gv = ((const float4*)g)[i];
        float4 uv = ((const float4*)u)[i];
        float4 r;
        r.x = gv.x / (1.f + __expf(-gv.x)) * uv.x;
        r.y = gv.y / (1.f + __expf(-gv.y)) * uv.y;
        r.z = gv.z / (1.f + __expf(-gv.z)) * uv.z;
        r.w = gv.w / (1.f + __expf(-gv.w)) * uv.w;
        ((float4*)o)[i] = r;
    }
}

// ---------------- host launcher ----------------
extern "C" void kernel_launch(void* const* d_in, const int* in_sizes, int n_in,
                              void* d_out, int out_size, void* d_ws, size_t ws_size,
                              hipStream_t stream) {
    const int*   p_ids   = (const int*)  d_in[0];
    const float* p_embed = (const float*)d_in[1];
    const float* p_cb    = (const float*)d_in[2];
    const int*   p_qidx  = (const int*)  d_in[3];  const float* p_qam = (const float*)d_in[4];
    const float* p_qA    = (const float*)d_in[5];  const float* p_qB  = (const float*)d_in[6];
    const int*   p_kidx  = (const int*)  d_in[7];  const float* p_kam = (const float*)d_in[8];
    const float* p_kA    = (const float*)d_in[9];  const float* p_kB  = (const float*)d_in[10];
    const int*   p_vidx  = (const int*)  d_in[11]; const float* p_vam = (const float*)d_in[12];
    const float* p_vA    = (const float*)d_in[13]; const float* p_vB  = (const float*)d_in[14];
    const int*   p_oidx  = (const int*)  d_in[15]; const float* p_oam = (const float*)d_in[16];
    const float* p_oA    = (const float*)d_in[17]; const float* p_oB  = (const float*)d_in[18];
    const int*   p_gidx  = (const int*)  d_in[19]; const float* p_gam = (const float*)d_in[20];
    const float* p_gA    = (const float*)d_in[21]; const float* p_gB  = (const float*)d_in[22];
    const int*   p_uidx  = (const int*)  d_in[23]; const float* p_uam = (const float*)d_in[24];
    const float* p_uA    = (const float*)d_in[25]; const float* p_uB  = (const float*)d_in[26];
    const int*   p_didx  = (const int*)  d_in[27]; const float* p_dam = (const float*)d_in[28];
    const float* p_dA    = (const float*)d_in[29]; const float* p_dB  = (const float*)d_in[30];
    const float* p_ln1   = (const float*)d_in[31];
    const float* p_ln2   = (const float*)d_in[32];
    const float* p_fn    = (const float*)d_in[33];
    const int*   p_lmidx = (const int*)  d_in[34]; const float* p_lmam = (const float*)d_in[35];

    float* hbuf = (float*)d_ws;                      // [SEQ][H]
    float* xbuf = hbuf + (size_t)SEQ * H;            // [SEQ][H]
    float* qb   = xbuf + (size_t)SEQ * H;            // [SEQ][H]
    float* kb   = qb   + (size_t)SEQ * H;            // [SEQ][KVD]
    float* vb   = kb   + (size_t)SEQ * KVD;          // [SEQ][KVD]
    float* ctx  = vb   + (size_t)SEQ * KVD;          // [SEQ][H]
    float* gate = ctx  + (size_t)SEQ * H;            // [SEQ][IDIM]
    float* up   = gate + (size_t)SEQ * IDIM;         // [SEQ][IDIM]
    float* attn = up   + (size_t)SEQ * IDIM;         // [NH][SEQ][SEQ]
    float* tbuf = attn;                              // alias: lora tmps live in attn scratch
                                                     // (attn only used between k_scores and k_ctx)

    k_embed<<<SEQ, 256, 0, stream>>>(p_ids, p_embed, hbuf);

    for (int l = 0; l < LAYERS; ++l) {
        const int*   qi  = p_qidx + (size_t)l * H * H;      const float* qa = p_qam + (size_t)l * (H*H/64);
        const float* qAl = p_qA + (size_t)l * RR * H;       const float* qBl = p_qB + (size_t)l * H * RR;
        const int*   ki  = p_kidx + (size_t)l * KVD * H;    const float* ka = p_kam + (size_t)l * (KVD*H/64);
        const float* kAl = p_kA + (size_t)l * RR * H;       const float* kBl = p_kB + (size_t)l * KVD * RR;
        const int*   vi  = p_vidx + (size_t)l * KVD * H;    const float* va = p_vam + (size_t)l * (KVD*H/64);
        const float* vAl = p_vA + (size_t)l * RR * H;       const float* vBl = p_vB + (size_t)l * KVD * RR;
        const int*   oi  = p_oidx + (size_t)l * H * H;      const float* oa = p_oam + (size_t)l * (H*H/64);
        const float* oAl = p_oA + (size_t)l * RR * H;       const float* oBl = p_oB + (size_t)l * H * RR;
        const int*   gi  = p_gidx + (size_t)l * IDIM * H;   const float* ga = p_gam + (size_t)l * (IDIM*H/64);
        const float* gAl = p_gA + (size_t)l * RR * H;       const float* gBl = p_gB + (size_t)l * IDIM * RR;
        const int*   ui  = p_uidx + (size_t)l * IDIM * H;   const float* ua = p_uam + (size_t)l * (IDIM*H/64);
        const float* uAl = p_uA + (size_t)l * RR * H;       const float* uBl = p_uB + (size_t)l * IDIM * RR;
        const int*   di  = p_didx + (size_t)l * H * IDIM;   const float* da = p_dam + (size_t)l * (H*IDIM/64);
        const float* dAl = p_dA + (size_t)l * RR * IDIM;    const float* dBl = p_dB + (size_t)l * H * RR;

        // ---- attention block ----
        k_rmsnorm<<<SEQ, 256, 0, stream>>>(hbuf, p_ln1 + (size_t)l * H, xbuf);
        hipMemsetAsync(tbuf, 0, 3 * (size_t)SEQ * RR * sizeof(float), stream);
        k_lora3<<<dim3(8,3,8), 256, 0, stream>>>(xbuf, qAl, kAl, vAl, tbuf, H, 128);
        k_gemm<true,false><<<dim3(4,8), 256, 0, stream>>>(
            xbuf, qi, qa, p_cb, tbuf,                qBl, qb, H,   H);
        k_gemm<true,false><<<dim3(4,2), 256, 0, stream>>>(
            xbuf, ki, ka, p_cb, tbuf + SEQ*RR,       kBl, kb, KVD, H);
        k_gemm<true,false><<<dim3(4,2), 256, 0, stream>>>(
            xbuf, vi, va, p_cb, tbuf + 2*SEQ*RR,     vBl, vb, KVD, H);

        k_rope<<<dim3(SEQ, NH + NKV), 64, 0, stream>>>(qb, kb);
        k_scores<<<dim3(SEQ/16, NH), 256, 0, stream>>>(qb, kb, attn);
        k_ctx<<<dim3(SEQ/64, NH), 256, 0, stream>>>(attn, vb, ctx);

        hipMemsetAsync(tbuf, 0, (size_t)SEQ * RR * sizeof(float), stream);
        k_lora3<<<dim3(8,1,8), 256, 0, stream>>>(ctx, oAl, oAl, oAl, tbuf, H, 128);
        k_gemm<true,true><<<dim3(4,8), 256, 0, stream>>>(
            ctx, oi, oa, p_cb, tbuf, oBl, hbuf, H, H);

        // ---- MLP block ----
        k_rmsnorm<<<SEQ, 256, 0, stream>>>(hbuf, p_ln2 + (size_t)l * H, xbuf);
        hipMemsetAsync(tbuf, 0, 2 * (size_t)SEQ * RR * sizeof(float), stream);
        k_lora3<<<dim3(8,2,8), 256, 0, stream>>>(xbuf, gAl, uAl, uAl, tbuf, H, 128);
        k_gemm<true,false><<<dim3(4,22), 256, 0, stream>>>(
            xbuf, gi, ga, p_cb, tbuf,          gBl, gate, IDIM, H);
        k_gemm<true,false><<<dim3(4,22), 256, 0, stream>>>(
            xbuf, ui, ua, p_cb, tbuf + SEQ*RR, uBl, up,   IDIM, H);

        k_silu<<<(SEQ*IDIM/4 + 255)/256, 256, 0, stream>>>(gate, up, gate, SEQ*IDIM/4);

        hipMemsetAsync(tbuf, 0, (size_t)SEQ * RR * sizeof(float), stream);
        k_lora3<<<dim3(8,1,11), 256, 0, stream>>>(gate, dAl, dAl, dAl, tbuf, IDIM, 256);
        k_gemm<true,true><<<dim3(4,8), 256, 0, stream>>>(
            gate, di, da, p_cb, tbuf, dBl, hbuf, H, IDIM);
    }

    // final norm + quantized lm_head (no LoRA)
    k_rmsnorm<<<SEQ, 256, 0, stream>>>(hbuf, p_fn, xbuf);
    k_gemm<false,false><<<dim3(4,250), 256, 0, stream>>>(
        xbuf, p_lmidx, p_lmam, p_cb, nullptr, nullptr, (float*)d_out, VOCAB, H);
}

// Round 3
// 1275.843 us; speedup vs baseline: 3.1741x; 1.1930x over previous
//
#include <hip/hip_runtime.h>
#include <math.h>

// ---------------- model constants ----------------
constexpr int LAYERS = 2;
constexpr int H      = 1024;
constexpr int NH     = 16;
constexpr int HD     = 64;
constexpr int NKV    = 4;
constexpr int KVD    = 256;   // NKV*HD
constexpr int IDIM   = 2816;
constexpr int VOCAB  = 32000;
constexpr int RR     = 64;    // lora rank
constexpr int SEQ    = 512;
constexpr float LORA_SCALE = 0.25f;   // 16/64
constexpr float RMS_EPS    = 1e-6f;

typedef __attribute__((ext_vector_type(8))) __bf16 bf16x8;
typedef __attribute__((ext_vector_type(4))) __bf16 bf16x4;
typedef __attribute__((ext_vector_type(4))) float f32x4;

__device__ __forceinline__ float dot4(float4 a, float4 b) {
    return a.x*b.x + a.y*b.y + a.z*b.z + a.w*b.w;
}

__device__ __forceinline__ bf16x8 pack8(float4 a, float4 b) {
    bf16x8 p;
    p[0] = (__bf16)a.x; p[1] = (__bf16)a.y; p[2] = (__bf16)a.z; p[3] = (__bf16)a.w;
    p[4] = (__bf16)b.x; p[5] = (__bf16)b.y; p[6] = (__bf16)b.z; p[7] = (__bf16)b.w;
    return p;
}

__device__ __forceinline__ bf16x8 dq8(int4 a, int4 b, float amv, const float* cbs) {
    bf16x8 p;
    p[0] = (__bf16)(cbs[a.x]*amv); p[1] = (__bf16)(cbs[a.y]*amv);
    p[2] = (__bf16)(cbs[a.z]*amv); p[3] = (__bf16)(cbs[a.w]*amv);
    p[4] = (__bf16)(cbs[b.x]*amv); p[5] = (__bf16)(cbs[b.y]*amv);
    p[6] = (__bf16)(cbs[b.z]*amv); p[7] = (__bf16)(cbs[b.w]*amv);
    return p;
}

// ---------------- embedding gather ----------------
__global__ __launch_bounds__(256) void k_embed(const int* __restrict__ ids,
                                               const float* __restrict__ embed,
                                               float* __restrict__ h) {
    int s = blockIdx.x;
    int t = threadIdx.x;
    const float4* src = (const float4*)(embed + (size_t)ids[s] * H);
    float4* dst = (float4*)(h + (size_t)s * H);
    dst[t] = src[t];
}

// ---------------- rmsnorm (fp32 in -> bf16 out) ----------------
__global__ __launch_bounds__(256) void k_rmsnorm(const float* __restrict__ h,
                                                 const float* __restrict__ w,
                                                 __bf16* __restrict__ x) {
    __shared__ float red[4];
    int s = blockIdx.x, t = threadIdx.x;
    float4 a = ((const float4*)(h + (size_t)s * H))[t];
    float ss = a.x*a.x + a.y*a.y + a.z*a.z + a.w*a.w;
    #pragma unroll
    for (int o = 32; o > 0; o >>= 1) ss += __shfl_xor(ss, o, 64);
    if ((t & 63) == 0) red[t >> 6] = ss;
    __syncthreads();
    float tot = red[0] + red[1] + red[2] + red[3];
    float scale = rsqrtf(tot * (1.0f / H) + RMS_EPS);
    float4 wv = ((const float4*)w)[t];
    bf16x4 o4;
    o4[0] = (__bf16)(a.x*scale*wv.x); o4[1] = (__bf16)(a.y*scale*wv.y);
    o4[2] = (__bf16)(a.z*scale*wv.z); o4[3] = (__bf16)(a.w*scale*wv.w);
    *(bf16x4*)&x[(size_t)s * H + t * 4] = o4;
}

// ---------------- unified fused dequant + LoRA MFMA GEMM ----------------
// y[512, N] (+)= x16[512,K] @ dequant(widx,am,cb)^T  + LORA_S*(x16@lA^T)@lB^T
// 128x128 tile, 4 waves (2x2), wave 64x64 via 4x4 mfma_f32_16x16x32_bf16.
// Block swizzle: same-N M-blocks get IDs equal mod 8 -> same XCD -> shared L2.
// EPI: 0 = store fp32, 1 = add into fp32 (residual), 2 = silu-combine:
//      read gate fp32 from y, write bf16(silu(gate)*acc) to y2.
struct GSeg {
    const int* widx; const float* am; const float* lA; const float* lB;
    float* y; int N; int ntiles;
};

template<int NSEG, bool LORA, int EPI>
__global__ __launch_bounds__(256) void k_gemm(
    const __bf16* __restrict__ x, const float* __restrict__ cb,
    GSeg s0, GSeg s1, GSeg s2, int K, int ntTotal, __bf16* __restrict__ y2)
{
    __shared__ __align__(16) __bf16 As[128][64];
    __shared__ __align__(16) __bf16 Bs[128][64];
    __shared__ __align__(16) __bf16 La[LORA ? 64 : 1][64];
    __shared__ float cbs[16];

    // XCD swizzle: id groups of 32 = 8 n-tiles x 4 m-tiles; XCD ~ id%8 = n%8
    const int id = blockIdx.x + (blockIdx.y << 2);
    const int mtile = (id >> 3) & 3;
    int n = ((id >> 5) << 3) + (id & 7);
    if (n >= ntTotal) return;

    const int* widx; const float* am; const float* lA; const float* lB;
    float* y; int N;
    if (NSEG == 1 || n < s0.ntiles) {
        widx=s0.widx; am=s0.am; lA=s0.lA; lB=s0.lB; y=s0.y; N=s0.N;
    } else if (NSEG == 2 || (n - s0.ntiles) < s1.ntiles) {
        n -= s0.ntiles;
        widx=s1.widx; am=s1.am; lA=s1.lA; lB=s1.lB; y=s1.y; N=s1.N;
    } else {
        n -= s0.ntiles + s1.ntiles;
        widx=s2.widx; am=s2.am; lA=s2.lA; lB=s2.lB; y=s2.y; N=s2.N;
    }
    const int sbase = mtile * 128;
    const int nbase = n * 128;
    const int t    = threadIdx.x;
    const int lane = t & 63;
    const int wave = t >> 6;
    const int wm = (wave >> 1) * 64;
    const int wn = (wave & 1) * 64;
    if (t < 16) cbs[t] = cb[t];
    const int srow = t >> 3;          // 0..31
    const int scol = (t & 7) * 8;     // 0,8,..,56
    const int KB   = K >> 6;

    f32x4 acc[4][4];
    f32x4 accl[4][4];
    const f32x4 fz = {0.f, 0.f, 0.f, 0.f};
    #pragma unroll
    for (int i = 0; i < 4; ++i)
        #pragma unroll
        for (int j = 0; j < 4; ++j) { acc[i][j] = fz; if constexpr (LORA) accl[i][j] = fz; }

    __syncthreads();   // cbs visible

    for (int k0 = 0; k0 < K; k0 += 64) {
        #pragma unroll
        for (int p = 0; p < 4; ++p) {   // A: bf16 copy
            int row = p * 32 + srow;
            *(bf16x8*)&As[row][scol] =
                *(const bf16x8*)&x[(size_t)(sbase + row) * K + k0 + scol];
        }
        #pragma unroll
        for (int p = 0; p < 4; ++p) {   // B: dequant
            int row = p * 32 + srow;
            const int* ip = &widx[(size_t)(nbase + row) * K + k0 + scol];
            int4 i0 = *(const int4*)ip;
            int4 i1 = *(const int4*)(ip + 4);
            float amv = am[(size_t)(nbase + row) * KB + (k0 >> 6)];
            *(bf16x8*)&Bs[row][scol] = dq8(i0, i1, amv, cbs);
        }
        if constexpr (LORA) {           // lora A tile [64][64]
            #pragma unroll
            for (int p = 0; p < 2; ++p) {
                int r = p * 32 + srow;
                const float* lp = &lA[(size_t)r * K + k0 + scol];
                *(bf16x8*)&La[r][scol] = pack8(*(const float4*)lp, *(const float4*)(lp + 4));
            }
        }
        __syncthreads();
        #pragma unroll
        for (int s = 0; s < 2; ++s) {
            bf16x8 a[4], b[4];
            #pragma unroll
            for (int mi = 0; mi < 4; ++mi)
                a[mi] = *(bf16x8*)&As[wm + mi*16 + (lane & 15)][s*32 + (lane >> 4)*8];
            #pragma unroll
            for (int ni = 0; ni < 4; ++ni)
                b[ni] = *(bf16x8*)&Bs[wn + ni*16 + (lane & 15)][s*32 + (lane >> 4)*8];
            #pragma unroll
            for (int mi = 0; mi < 4; ++mi)
                #pragma unroll
                for (int ni = 0; ni < 4; ++ni)
                    acc[mi][ni] = __builtin_amdgcn_mfma_f32_16x16x32_bf16(
                        a[mi], b[ni], acc[mi][ni], 0, 0, 0);
            if constexpr (LORA) {
                bf16x8 bl[4];
                #pragma unroll
                for (int ni = 0; ni < 4; ++ni)
                    bl[ni] = *(bf16x8*)&La[ni*16 + (lane & 15)][s*32 + (lane >> 4)*8];
                #pragma unroll
                for (int mi = 0; mi < 4; ++mi)
                    #pragma unroll
                    for (int ni = 0; ni < 4; ++ni)
                        accl[mi][ni] = __builtin_amdgcn_mfma_f32_16x16x32_bf16(
                            a[mi], bl[ni], accl[mi][ni], 0, 0, 0);
            }
        }
        __syncthreads();
    }

    if constexpr (LORA) {
        // lt (C/D layout, waves with wn==0 own unique rows) -> As as bf16
        if (wn == 0) {
            const int cr = (lane >> 4) * 4, cc = lane & 15;
            #pragma unroll
            for (int mi = 0; mi < 4; ++mi)
                #pragma unroll
                for (int ni = 0; ni < 4; ++ni)
                    #pragma unroll
                    for (int r = 0; r < 4; ++r)
                        As[wm + mi*16 + cr + r][ni*16 + cc] =
                            (__bf16)(LORA_SCALE * accl[mi][ni][r]);
        }
        #pragma unroll
        for (int p = 0; p < 4; ++p) {   // Bm tile [128][64]
            int row = p * 32 + srow;
            const float* bp = &lB[(size_t)(nbase + row) * RR + scol];
            *(bf16x8*)&Bs[row][scol] = pack8(*(const float4*)bp, *(const float4*)(bp + 4));
        }
        __syncthreads();
        #pragma unroll
        for (int s = 0; s < 2; ++s) {
            bf16x8 a[4], b[4];
            #pragma unroll
            for (int mi = 0; mi < 4; ++mi)
                a[mi] = *(bf16x8*)&As[wm + mi*16 + (lane & 15)][s*32 + (lane >> 4)*8];
            #pragma unroll
            for (int ni = 0; ni < 4; ++ni)
                b[ni] = *(bf16x8*)&Bs[wn + ni*16 + (lane & 15)][s*32 + (lane >> 4)*8];
            #pragma unroll
            for (int mi = 0; mi < 4; ++mi)
                #pragma unroll
                for (int ni = 0; ni < 4; ++ni)
                    acc[mi][ni] = __builtin_amdgcn_mfma_f32_16x16x32_bf16(
                        a[mi], b[ni], acc[mi][ni], 0, 0, 0);
        }
    }

    // epilogue: C/D layout col=lane&15, row=(lane>>4)*4+reg
    const int cr = (lane >> 4) * 4;
    const int cc = lane & 15;
    #pragma unroll
    for (int mi = 0; mi < 4; ++mi) {
        #pragma unroll
        for (int ni = 0; ni < 4; ++ni) {
            int gr = sbase + wm + mi * 16 + cr;
            int gc = nbase + wn + ni * 16 + cc;
            #pragma unroll
            for (int r = 0; r < 4; ++r) {
                size_t off = (size_t)(gr + r) * N + gc;
                if constexpr (EPI == 0) y[off] = acc[mi][ni][r];
                if constexpr (EPI == 1) y[off] += acc[mi][ni][r];
                if constexpr (EPI == 2) {
                    float g = y[off];
                    float val = g / (1.f + __expf(-g)) * acc[mi][ni][r];
                    y2[off] = (__bf16)val;
                }
            }
        }
    }
}

// ---------------- RoPE (rotate-half) on q and k in place ----------------
__global__ __launch_bounds__(256) void k_rope(float* __restrict__ q, float* __restrict__ k) {
    int s  = blockIdx.x;
    int hs = blockIdx.y * 4 + (threadIdx.x >> 6);   // 0..19
    int d  = threadIdx.x & 63;
    float* p = (hs < NH) ? q + ((size_t)s * NH + hs) * HD
                         : k + ((size_t)s * NKV + (hs - NH)) * HD;
    int j = d & 31;
    float inv = exp2f(-(float)(2 * j) * (13.287712379549449f / 64.0f));
    float ang = (float)s * inv;
    float sn, c;
    __sincosf(ang, &sn, &c);
    float xv = p[d];
    float other = (d < 32) ? -p[d + 32] : p[d - 32];   // wave-lockstep safe
    p[d] = xv * c + other * sn;
}

// ---------------- attention scores + causal softmax ----------------
__global__ __launch_bounds__(256) void k_scores(const float* __restrict__ q,
                                                const float* __restrict__ k,
                                                float* __restrict__ attn) {
    int qt = blockIdx.x;
    int h  = blockIdx.y;
    int kvh = h >> 2;
    __shared__ float qs[16][68];
    __shared__ float ks[64][68];
    __shared__ float sc[16][528];
    int t = threadIdx.x;
    { int row = t >> 4; int c4 = (t & 15) << 2;
      *(float4*)&qs[row][c4] = *(const float4*)&q[(size_t)(qt*16 + row) * H + h * HD + c4]; }
    for (int c = 0; c < 8; ++c) {
        #pragma unroll
        for (int i = 0; i < 4; ++i) {
            int id = t + i * 256; int row = id >> 4; int c4 = (id & 15) << 2;
            *(float4*)&ks[row][c4] = *(const float4*)&k[(size_t)(c*64 + row) * KVD + kvh * HD + c4];
        }
        __syncthreads();
        int r  = t >> 4;
        int cc = (t & 15) << 2;
        float4 acc = make_float4(0.f, 0.f, 0.f, 0.f);
        #pragma unroll
        for (int kk = 0; kk < 64; kk += 4) {
            float4 a = *(const float4*)&qs[r][kk];
            acc.x += dot4(a, *(const float4*)&ks[cc + 0][kk]);
            acc.y += dot4(a, *(const float4*)&ks[cc + 1][kk]);
            acc.z += dot4(a, *(const float4*)&ks[cc + 2][kk]);
            acc.w += dot4(a, *(const float4*)&ks[cc + 3][kk]);
        }
        acc.x *= 0.125f; acc.y *= 0.125f; acc.z *= 0.125f; acc.w *= 0.125f;
        *(float4*)&sc[r][c * 64 + cc] = acc;
        __syncthreads();
    }
    int r = t >> 4, lane = t & 15;
    int qpos = qt * 16 + r;
    float mx = -1e30f;
    for (int c = lane; c < SEQ; c += 16) if (c <= qpos) mx = fmaxf(mx, sc[r][c]);
    #pragma unroll
    for (int o = 8; o > 0; o >>= 1) mx = fmaxf(mx, __shfl_xor(mx, o, 16));
    float sum = 0.f;
    for (int c = lane; c < SEQ; c += 16) {
        float e = (c <= qpos) ? __expf(sc[r][c] - mx) : 0.f;
        sc[r][c] = e; sum += e;
    }
    #pragma unroll
    for (int o = 8; o > 0; o >>= 1) sum += __shfl_xor(sum, o, 16);
    float inv = 1.0f / sum;
    for (int c = lane; c < SEQ; c += 16)
        attn[((size_t)h * SEQ + qpos) * SEQ + c] = sc[r][c] * inv;
}

// ---------------- ctx = attn @ v -> bf16 ----------------
__global__ __launch_bounds__(256) void k_ctx(const float* __restrict__ attn,
                                             const float* __restrict__ v,
                                             __bf16* __restrict__ ctx) {
    int qt = blockIdx.x, h = blockIdx.y, kvh = h >> 2;
    __shared__ float as_[64][68];
    __shared__ float vs[64][68];
    int t = threadIdx.x;
    float acc[4][4] = {};
    for (int c = 0; c <= qt; ++c) {
        #pragma unroll
        for (int i = 0; i < 4; ++i) {
            int id = t + i * 256; int row = id >> 4; int c4 = (id & 15) << 2;
            *(float4*)&as_[row][c4] = *(const float4*)&attn[((size_t)h*SEQ + qt*64 + row) * SEQ + c*64 + c4];
            *(float4*)&vs[row][c4]  = *(const float4*)&v[(size_t)(c*64 + row) * KVD + kvh * HD + c4];
        }
        __syncthreads();
        int ty = (t >> 4) * 4, tx = (t & 15) * 4;
        #pragma unroll
        for (int kk = 0; kk < 64; ++kk) {
            float4 b = *(const float4*)&vs[kk][tx];
            #pragma unroll
            for (int i = 0; i < 4; ++i) {
                float a = as_[ty + i][kk];
                acc[i][0] += a * b.x; acc[i][1] += a * b.y;
                acc[i][2] += a * b.z; acc[i][3] += a * b.w;
            }
        }
        __syncthreads();
    }
    int ty = (t >> 4) * 4, tx = (t & 15) * 4;
    #pragma unroll
    for (int i = 0; i < 4; ++i) {
        bf16x4 o4;
        o4[0] = (__bf16)acc[i][0]; o4[1] = (__bf16)acc[i][1];
        o4[2] = (__bf16)acc[i][2]; o4[3] = (__bf16)acc[i][3];
        *(bf16x4*)&ctx[(size_t)(qt*64 + ty + i) * H + h * HD + tx] = o4;
    }
}

// ---------------- host launcher ----------------
extern "C" void kernel_launch(void* const* d_in, const int* in_sizes, int n_in,
                              void* d_out, int out_size, void* d_ws, size_t ws_size,
                              hipStream_t stream) {
    const int*   p_ids   = (const int*)  d_in[0];
    const float* p_embed = (const float*)d_in[1];
    const float* p_cb    = (const float*)d_in[2];
    const int*   p_qidx  = (const int*)  d_in[3];  const float* p_qam = (const float*)d_in[4];
    const float* p_qA    = (const float*)d_in[5];  const float* p_qB  = (const float*)d_in[6];
    const int*   p_kidx  = (const int*)  d_in[7];  const float* p_kam = (const float*)d_in[8];
    const float* p_kA    = (const float*)d_in[9];  const float* p_kB  = (const float*)d_in[10];
    const int*   p_vidx  = (const int*)  d_in[11]; const float* p_vam = (const float*)d_in[12];
    const float* p_vA    = (const float*)d_in[13]; const float* p_vB  = (const float*)d_in[14];
    const int*   p_oidx  = (const int*)  d_in[15]; const float* p_oam = (const float*)d_in[16];
    const float* p_oA    = (const float*)d_in[17]; const float* p_oB  = (const float*)d_in[18];
    const int*   p_gidx  = (const int*)  d_in[19]; const float* p_gam = (const float*)d_in[20];
    const float* p_gA    = (const float*)d_in[21]; const float* p_gB  = (const float*)d_in[22];
    const int*   p_uidx  = (const int*)  d_in[23]; const float* p_uam = (const float*)d_in[24];
    const float* p_uA    = (const float*)d_in[25]; const float* p_uB  = (const float*)d_in[26];
    const int*   p_didx  = (const int*)  d_in[27]; const float* p_dam = (const float*)d_in[28];
    const float* p_dA    = (const float*)d_in[29]; const float* p_dB  = (const float*)d_in[30];
    const float* p_ln1   = (const float*)d_in[31];
    const float* p_ln2   = (const float*)d_in[32];
    const float* p_fn    = (const float*)d_in[33];
    const int*   p_lmidx = (const int*)  d_in[34]; const float* p_lmam = (const float*)d_in[35];

    char* w = (char*)d_ws;
    const size_t MB = 1024 * 1024;
    float*  hbuf  = (float*) (w + 0);          // 512x1024 f32  (2 MB)
    __bf16* xb16  = (__bf16*)(w + 2*MB);       // 512x1024 bf16 (1 MB)
    float*  qb    = (float*) (w + 3*MB);       // 512x1024 f32  (2 MB)
    float*  kb    = (float*) (w + 5*MB);       // 512x256  f32  (0.5 MB)
    float*  vb    = (float*) (w + 5*MB + 512*1024);  // 512x256 f32 (0.5 MB)
    __bf16* ctx16 = (__bf16*)(w + 6*MB);       // 512x1024 bf16 (1 MB)
    float*  attn  = (float*) (w + 7*MB);       // 16x512x512 f32 (16.8 MB)
    __bf16* g16   = (__bf16*)(w + 7*MB);       // alias: 512x2816 bf16 (2.9 MB)
    float*  gatef = (float*) (w + 11*MB);      // alias: 512x2816 f32  (5.8 MB)

    const GSeg znull = {nullptr, nullptr, nullptr, nullptr, nullptr, 0, 0};

    k_embed<<<SEQ, 256, 0, stream>>>(p_ids, p_embed, hbuf);

    for (int l = 0; l < LAYERS; ++l) {
        const int*   qi  = p_qidx + (size_t)l * H * H;      const float* qa = p_qam + (size_t)l * (H*H/64);
        const float* qAl = p_qA + (size_t)l * RR * H;       const float* qBl = p_qB + (size_t)l * H * RR;
        const int*   ki  = p_kidx + (size_t)l * KVD * H;    const float* ka = p_kam + (size_t)l * (KVD*H/64);
        const float* kAl = p_kA + (size_t)l * RR * H;       const float* kBl = p_kB + (size_t)l * KVD * RR;
        const int*   vi  = p_vidx + (size_t)l * KVD * H;    const float* va = p_vam + (size_t)l * (KVD*H/64);
        const float* vAl = p_vA + (size_t)l * RR * H;       const float* vBl = p_vB + (size_t)l * KVD * RR;
        const int*   oi  = p_oidx + (size_t)l * H * H;      const float* oa = p_oam + (size_t)l * (H*H/64);
        const float* oAl = p_oA + (size_t)l * RR * H;       const float* oBl = p_oB + (size_t)l * H * RR;
        const int*   gi  = p_gidx + (size_t)l * IDIM * H;   const float* ga = p_gam + (size_t)l * (IDIM*H/64);
        const float* gAl = p_gA + (size_t)l * RR * H;       const float* gBl = p_gB + (size_t)l * IDIM * RR;
        const int*   ui  = p_uidx + (size_t)l * IDIM * H;   const float* ua = p_uam + (size_t)l * (IDIM*H/64);
        const float* uAl = p_uA + (size_t)l * RR * H;       const float* uBl = p_uB + (size_t)l * IDIM * RR;
        const int*   di  = p_didx + (size_t)l * H * IDIM;   const float* da = p_dam + (size_t)l * (H*IDIM/64);
        const float* dAl = p_dA + (size_t)l * RR * IDIM;    const float* dBl = p_dB + (size_t)l * H * RR;

        // ---- attention block ----
        k_rmsnorm<<<SEQ, 256, 0, stream>>>(hbuf, p_ln1 + (size_t)l * H, xb16);
        {
            GSeg sq = {qi, qa, qAl, qBl, qb, H,   8};
            GSeg sk = {ki, ka, kAl, kBl, kb, KVD, 2};
            GSeg sv = {vi, va, vAl, vBl, vb, KVD, 2};
            k_gemm<3,true,0><<<dim3(4,16), 256, 0, stream>>>(
                xb16, p_cb, sq, sk, sv, H, 12, nullptr);
        }
        k_rope<<<dim3(SEQ, 5), 256, 0, stream>>>(qb, kb);
        k_scores<<<dim3(SEQ/16, NH), 256, 0, stream>>>(qb, kb, attn);
        k_ctx<<<dim3(SEQ/64, NH), 256, 0, stream>>>(attn, vb, ctx16);
        {
            GSeg so = {oi, oa, oAl, oBl, hbuf, H, 8};
            k_gemm<1,true,1><<<dim3(4,8), 256, 0, stream>>>(
                ctx16, p_cb, so, znull, znull, H, 8, nullptr);
        }

        // ---- MLP block ----
        k_rmsnorm<<<SEQ, 256, 0, stream>>>(hbuf, p_ln2 + (size_t)l * H, xb16);
        {
            GSeg sg = {gi, ga, gAl, gBl, gatef, IDIM, 22};
            k_gemm<1,true,0><<<dim3(4,24), 256, 0, stream>>>(
                xb16, p_cb, sg, znull, znull, H, 22, nullptr);
        }
        {   // up + fused silu(gate)*up -> g16 (bf16)
            GSeg su = {ui, ua, uAl, uBl, gatef, IDIM, 22};
            k_gemm<1,true,2><<<dim3(4,24), 256, 0, stream>>>(
                xb16, p_cb, su, znull, znull, H, 22, g16);
        }
        {
            GSeg sd = {di, da, dAl, dBl, hbuf, H, 8};
            k_gemm<1,true,1><<<dim3(4,8), 256, 0, stream>>>(
                g16, p_cb, sd, znull, znull, IDIM, 8, nullptr);
        }
    }

    // final norm + quantized lm_head (no LoRA)
    k_rmsnorm<<<SEQ, 256, 0, stream>>>(hbuf, p_fn, xb16);
    {
        GSeg sl = {p_lmidx, p_lmam, nullptr, nullptr, (float*)d_out, VOCAB, 250};
        k_gemm<1,false,0><<<dim3(4,256), 256, 0, stream>>>(
            xb16, p_cb, sl, znull, znull, H, 250, nullptr);
    }
}